// Round 16
// baseline (366.181 us; speedup 1.0000x reference)
//
#include <hip/hip_runtime.h>

// ConvLSTM (B=16,H=128,W=128,CIN=1,HID=64, 2 cells, h=c=0 -> f-gate dead)
// Round 16: gates64 -> block = 256px(2 rows) x 80 gate-ch; all 4 waves share
// ONE ch-group -> identical weight addresses (L1 broadcast), weight L2
// traffic 1.5GB -> 369MB. Per-wave tile = round-8 proven acc[4][5].
// LDS 66.5KB (gfx950 allows up to 160KB/WG). attn v5 kept (Ps overlay).
// Pipeline: repack -> gates1 -> attn<0> -> gates64 -> attn<1>(+outconv)

#define DEVFN __device__ __forceinline__

typedef __attribute__((ext_vector_type(8))) short short8;
typedef __attribute__((ext_vector_type(4))) float f32x4;

DEVFN float sigmoidf_(float z) { return 1.0f / (1.0f + __expf(-z)); }

DEVFN float tanhf_(float x) {  // fast tanh; correct limits at +-inf
    float e = __expf(2.0f * x);
    return 1.0f - 2.0f / (e + 1.0f);
}

DEVFN unsigned short f2bf(float f) {  // RNE fp32 -> bf16
    unsigned int u = __builtin_bit_cast(unsigned int, f);
    u += 0x7fffu + ((u >> 16) & 1u);
    return (unsigned short)(u >> 16);
}

DEVFN unsigned pkbf(float a, float b) {  // pack 2 fp32 -> 2 bf16 (RNE)
    return (unsigned)f2bf(a) | ((unsigned)f2bf(b) << 16);
}

// ---------------------------------------------------------------------------
// Repack.
//  pwc (bf16, 184320 el): lane-coalesced gates64 weights.
//    idx = (((g*18+kk)*4 + ng)*64 + lane)*8 + j
//    value = W[g][ch = ng*16+(lane&15)][kcol = kk*32+(lane>>4)*8+j]
//  pw0 (fp32) [5][9][64]; qkv/proj -> bf16 (row-major).
// ---------------------------------------------------------------------------
__global__ __launch_bounds__(256) void repack_kernel(
    const float* __restrict__ cw0, const float* __restrict__ pxw0, const float* __restrict__ pyw0,
    const float* __restrict__ cw1, const float* __restrict__ pxw1, const float* __restrict__ pyw1,
    const float* __restrict__ qkvw0, const float* __restrict__ projw0,
    const float* __restrict__ qkvw1, const float* __restrict__ projw1,
    unsigned short* __restrict__ pwc, float* __restrict__ pw0,
    unsigned short* __restrict__ qb0, unsigned short* __restrict__ pjb0,
    unsigned short* __restrict__ qb1, unsigned short* __restrict__ pjb1)
{
    int idx = blockIdx.x * 256 + threadIdx.x;
    if (idx < 184320) {  // 90 * 2048
        int j = idx & 7;
        int lane = (idx >> 3) & 63;
        int ng = (idx >> 9) & 3;
        int t = idx >> 11;          // g*18 + kk
        int kk = t % 18, g = t / 18;
        int c = ng * 16 + (lane & 15);
        int kcol = kk * 32 + (lane >> 4) * 8 + j;
        int pos = kcol >> 6, cin = kcol & 63;
        float v;
        if (g == 0)      v = cw1[((c      ) * 128 + cin) * 9 + pos];  // ci
        else if (g == 1) v = cw1[((128 + c) * 128 + cin) * 9 + pos];  // co
        else if (g == 2) v = cw1[((192 + c) * 128 + cin) * 9 + pos];  // cg
        else if (g == 3) v = pxw1[(c * 64 + cin) * 9 + pos];          // px
        else             v = pyw1[(c * 64 + cin) * 9 + pos];          // py
        pwc[idx] = f2bf(v);
    } else if (idx < 187200) {  // + 5*9*64
        int i2 = idx - 184320;
        int g = i2 / (9 * 64);
        int rem = i2 - g * (9 * 64);
        int pos = rem >> 6, c = rem & 63;
        float v;
        if (g == 0)      v = cw0[(c      ) * 585 + pos];
        else if (g == 1) v = cw0[(128 + c) * 585 + pos];
        else if (g == 2) v = cw0[(192 + c) * 585 + pos];
        else if (g == 3) v = pxw0[c * 9 + pos];
        else             v = pyw0[c * 9 + pos];
        pw0[i2] = v;
    } else if (idx < 187200 + 12288) {
        int i = idx - 187200;           qb0[i] = f2bf(qkvw0[i]);
    } else if (idx < 187200 + 24576) {
        int i = idx - 187200 - 12288;   qb1[i] = f2bf(qkvw1[i]);
    } else if (idx < 187200 + 24576 + 4096) {
        int i = idx - 187200 - 24576;   pjb0[i] = f2bf(projw0[i]);
    } else if (idx < 187200 + 24576 + 8192) {
        int i = idx - 187200 - 28672;   pjb1[i] = f2bf(projw1[i]);
    }
}

// ---------------------------------------------------------------------------
// Layer-0 gates (CIN=1): memory-bound; bf16 output. (round-8 proven)
// ---------------------------------------------------------------------------
__global__ __launch_bounds__(256) void gates1_kernel(
    const float* __restrict__ x, const float* __restrict__ pw,
    const float* __restrict__ cb, unsigned short* __restrict__ dst)
{
    const int idx = blockIdx.x * 256 + threadIdx.x;
    const int pix = idx >> 4, ch0 = (idx & 15) * 4;
    const int b = pix >> 14, y = (pix >> 7) & 127, xq = pix & 127;

    float a[9];
#pragma unroll
    for (int dy = 0; dy < 3; ++dy)
#pragma unroll
        for (int dx = 0; dx < 3; ++dx) {
            int gy = y + dy - 1, gx = xq + dx - 1;
            a[dy * 3 + dx] = ((unsigned)gy < 128u && (unsigned)gx < 128u)
                ? x[(b * 128 + gy) * 128 + gx] : 0.f;
        }

    float acc[5][4];
#pragma unroll
    for (int g = 0; g < 5; ++g)
#pragma unroll
        for (int u = 0; u < 4; ++u) acc[g][u] = 0.f;

#pragma unroll
    for (int pos = 0; pos < 9; ++pos) {
        const float av = a[pos];
#pragma unroll
        for (int g = 0; g < 5; ++g) {
            const float4 w4 = *(const float4*)(pw + (g * 9 + pos) * 64 + ch0);
            acc[g][0] = fmaf(av, w4.x, acc[g][0]);
            acc[g][1] = fmaf(av, w4.y, acc[g][1]);
            acc[g][2] = fmaf(av, w4.z, acc[g][2]);
            acc[g][3] = fmaf(av, w4.w, acc[g][3]);
        }
    }

    float hv[4];
#pragma unroll
    for (int u = 0; u < 4; ++u) {
        float ci = acc[0][u] + cb[ch0 + u];
        float co = acc[1][u] + cb[128 + ch0 + u];
        float cg = acc[2][u] + cb[192 + ch0 + u];
        float iv = sigmoidf_(ci + acc[3][u]);
        float ov = sigmoidf_(co + acc[4][u]);
        float gv = tanhf_(cg + acc[4][u]);
        hv[u] = ov * tanhf_(iv * gv);
    }
    uint2 o;
    o.x = pkbf(hv[0], hv[1]);
    o.y = pkbf(hv[2], hv[3]);
    *(uint2*)(dst + (size_t)pix * 64 + ch0) = o;
}

// ---------------------------------------------------------------------------
// Layer-1 gates: bf16 MFMA implicit GEMM. Block = 256px (2 rows) x 80 gch
// (ONE ch-group, cg = bid&3). 4 waves x 64px, acc[4][5] (round-8 per-wave
// shape). All waves load IDENTICAL weight fragments -> L1 broadcast; weight
// L2 traffic 4x lower than round-8. LDS [4 rows][130 cols][64ch] = 66.5KB.
// ---------------------------------------------------------------------------
__global__ __launch_bounds__(256, 2) void gates64_kernel(
    const unsigned short* __restrict__ src, const unsigned short* __restrict__ wtc,
    const float* __restrict__ cb, unsigned short* __restrict__ dst)
{
    __shared__ unsigned short lds[4 * 130 * 64];  // 66560 B
    char* const sbase = (char*)lds;

    const int tid = threadIdx.x;
    const int bid = blockIdx.x;
    const int cg = bid & 3;            // channel group (shared by all waves)
    const int pxt = bid >> 2;          // pixel tile: 2 rows
    const int b = pxt >> 6, y2 = (pxt & 63) * 2;

    // stage A: rows y2-1..y2+2, cols -1..128 (130), bf16 copy, swizzled
    for (int i4 = tid; i4 < 4 * 130 * 8; i4 += 256) {
        int r = i4 / (130 * 8);
        int rem = i4 - r * (130 * 8);
        int xx = rem >> 3, c8 = rem & 7;
        int gy = y2 + r - 1, gx = xx - 1;
        uint4 wv = make_uint4(0, 0, 0, 0);
        if ((unsigned)gy < 128u && (unsigned)gx < 128u)
            wv = *(const uint4*)(src + (((size_t)(b * 128 + gy) * 128 + gx) * 64 + c8 * 8));
        int addr = ((r * 130 + xx) * 128 + c8 * 16) ^ ((xx & 7) << 4);
        *(uint4*)(sbase + addr) = wv;
    }
    __syncthreads();

    const int lane = tid & 63;
    const int wv_ = tid >> 6;          // 0..3: px group [64*wv_, 64*wv_+64)
    const int rp = wv_ >> 1;           // row-part (0: row y2, 1: row y2+1)
    const int cb64 = (wv_ & 1) * 64;   // col base within row
    const int r0 = lane & 15;
    const int hi = lane >> 4;
    const int wch = cg * 16 + r0;

    // shared weight base: fragment (g,kk) = wbase + (g*18+kk)*2048 shorts
    const unsigned short* wbase = wtc + (size_t)(cg * 64 + lane) * 8;

    f32x4 acc[4][5];
#pragma unroll
    for (int mt = 0; mt < 4; ++mt)
#pragma unroll
        for (int g = 0; g < 5; ++g) acc[mt][g] = (f32x4){0.f, 0.f, 0.f, 0.f};

#pragma unroll
    for (int kk = 0; kk < 18; ++kk) {
        const int pos = kk >> 1, dy = pos / 3, dx = pos % 3, chalf = kk & 1;
        const int swz = (((r0 + dx) & 7) << 4);
        short8 bfr[5];
#pragma unroll
        for (int g = 0; g < 5; ++g)
            bfr[g] = *(const short8*)(wbase + (g * 18 + kk) * 2048);
        short8 afr[4];
#pragma unroll
        for (int mt = 0; mt < 4; ++mt) {
            const int row = rp + dy;
            const int col = cb64 + mt * 16 + r0 + dx;
            const int addr = ((row * 130 + col) * 128 + chalf * 64 + hi * 16) ^ swz;
            afr[mt] = *(const short8*)(sbase + addr);
        }
#pragma unroll
        for (int mt = 0; mt < 4; ++mt)
#pragma unroll
            for (int g = 0; g < 5; ++g)
                acc[mt][g] = __builtin_amdgcn_mfma_f32_16x16x32_bf16(
                    afr[mt], bfr[g], acc[mt][g], 0, 0, 0);
    }

    const float bci = cb[wch], bco = cb[128 + wch], bcg = cb[192 + wch];
    const int rowbase = (b * 128 + y2) * 128;   // px 0..255 spans rows y2,y2+1
#pragma unroll
    for (int mt = 0; mt < 4; ++mt) {
#pragma unroll
        for (int rg = 0; rg < 4; ++rg) {
            const int px_i = wv_ * 64 + mt * 16 + hi * 4 + rg;
            float ci = acc[mt][0][rg] + bci;
            float co = acc[mt][1][rg] + bco;
            float cg_ = acc[mt][2][rg] + bcg;
            float pxv = acc[mt][3][rg];
            float pyv = acc[mt][4][rg];
            float iv = sigmoidf_(ci + pxv);
            float ov = sigmoidf_(co + pyv);
            float gv = tanhf_(cg_ + pyv);
            dst[(size_t)(rowbase + px_i) * 64 + wch] = f2bf(ov * tanhf_(iv * gv));
        }
    }
}

// ---------------------------------------------------------------------------
// Window attention v5 (3 barriers; Ps overlays dead Xs -> 40KB LDS).
// FUSE=1: fold the 1x1 outconv into the epilogue (h1 never hits HBM).
// ---------------------------------------------------------------------------
template <int FUSE>
__global__ __launch_bounds__(256, 3) void attn_kernel(
    const unsigned short* __restrict__ src,    // NHWC bf16 [16,128,128,64]
    const unsigned short* __restrict__ qkvwb,  // [192][64] bf16
    const unsigned short* __restrict__ projwb, // [64][64] bf16
    const float* __restrict__ projb,           // [64]
    unsigned short* __restrict__ dst,          // NHWC bf16 (FUSE=0)
    const float* __restrict__ outw,            // [64] (FUSE=1)
    const float* __restrict__ outb,            // [1]  (FUSE=1)
    float* __restrict__ out)                   // [16,128,128,1] (FUSE=1)
{
    __shared__ char sm[40960];
    char* const Xs = sm;             // [64 tok][128B] swz; DEAD after barrier 2
    char* const Ps = sm;             //   -> reused as [64 q][64key*2B] swz
    char* const Xo = sm + 8192;      // [64 tok][128B] swz
    char* const Qa = sm + 16384;     // [64 tok][64d*2B] swz
    char* const Ka = sm + 24576;     // [64 tok][64d*2B] swz
    char* const VT = sm + 32768;     // [64 d][64tok*2B] swz; reused as red[64][4]

    const int tid = threadIdx.x;
    const int lane = tid & 63;
    const int w = __builtin_amdgcn_readfirstlane(tid >> 6);
    const int lo = lane & 15, hi = lane >> 4;
    const int wid = blockIdx.x;
    const int b = wid >> 8, rem = wid & 255, wy = rem >> 4, wx = rem & 15;
    const int pixbase = (b * 128 + wy * 8) * 128 + wx * 8;

    // ---- stage X: bf16 copy, swizzled ----
    {
        const int t = tid >> 2, c0 = (tid & 3) * 16;
        const int pix = pixbase + (t >> 3) * 128 + (t & 7);
        const uint4* sp = (const uint4*)(src + (size_t)pix * 64 + c0);
        uint4 w0 = sp[0], w1 = sp[1];
        const int a = t * 128 + c0 * 2, sz = (t & 7) << 4;
        *(uint4*)(Xs + (a ^ sz)) = w0;
        *(uint4*)(Xs + ((a + 16) ^ sz)) = w1;
    }
    __syncthreads();  // barrier 1: Xs complete

    const int trow = w * 16 + lo;
    const int tswz = (lo & 7) << 4;

    // ---- QKV for ALL heads (wave w covers its token slice) ----
#pragma unroll
    for (int h = 0; h < 4; ++h) {
        f32x4 cq = {0.f, 0.f, 0.f, 0.f}, ck = cq, cv = cq;
#pragma unroll
        for (int ks = 0; ks < 2; ++ks) {
            const int koff = hi * 8 + ks * 32;
            short8 xb = *(const short8*)(Xs + ((trow * 128 + koff * 2) ^ tswz));
            short8 aq = *(const short8*)(qkvwb + (h * 16 + lo) * 64 + koff);
            short8 ak = *(const short8*)(qkvwb + (64 + h * 16 + lo) * 64 + koff);
            short8 bv = *(const short8*)(qkvwb + (128 + h * 16 + lo) * 64 + koff);
            cq = __builtin_amdgcn_mfma_f32_16x16x32_bf16(aq, xb, cq, 0, 0, 0);
            ck = __builtin_amdgcn_mfma_f32_16x16x32_bf16(ak, xb, ck, 0, 0, 0);
            cv = __builtin_amdgcn_mfma_f32_16x16x32_bf16(xb, bv, cv, 0, 0, 0);
        }
        uint2 qw, kw, vw;
        qw.x = pkbf(cq[0] * 0.125f, cq[1] * 0.125f);
        qw.y = pkbf(cq[2] * 0.125f, cq[3] * 0.125f);
        kw.x = pkbf(ck[0], ck[1]); kw.y = pkbf(ck[2], ck[3]);
        vw.x = pkbf(cv[0], cv[1]); vw.y = pkbf(cv[2], cv[3]);
        *(uint2*)(Qa + ((trow * 128 + (h * 16 + hi * 4) * 2) ^ tswz)) = qw;
        *(uint2*)(Ka + ((trow * 128 + (h * 16 + hi * 4) * 2) ^ tswz)) = kw;
        *(uint2*)(VT + (((h * 16 + lo) * 128 + (w * 16 + hi * 4) * 2) ^ ((lo & 7) << 4))) = vw;
    }
    __syncthreads();  // barrier 2: Qa/Ka/VT complete; Xs now dead -> Ps

    // ---- per head: scores + softmax + PV (wave-private P/Xo rows) ----
#pragma unroll 1
    for (int h = 0; h < 4; ++h) {
        const int hb = h * 32;
        short8 bq = *(const short8*)(Qa + ((trow * 128 + hb + (hi & 1) * 16) ^ tswz));
        f32x4 st[4];
#pragma unroll
        for (int mt = 0; mt < 4; ++mt) {
            short8 ak2 = *(const short8*)(Ka + (((mt * 16 + lo) * 128 + hb + (hi & 1) * 16) ^ ((lo & 7) << 4)));
            f32x4 z = {0.f, 0.f, 0.f, 0.f};
            st[mt] = __builtin_amdgcn_mfma_f32_16x16x32_bf16(ak2, bq, z, 0, 0, 0);
        }
        float mx = -1e30f;
#pragma unroll
        for (int mt = 0; mt < 4; ++mt)
#pragma unroll
            for (int r = 0; r < 4; ++r) mx = fmaxf(mx, st[mt][r]);
        mx = fmaxf(mx, __shfl_xor(mx, 16));
        mx = fmaxf(mx, __shfl_xor(mx, 32));
        float pv[16];
        float sum = 0.f;
#pragma unroll
        for (int mt = 0; mt < 4; ++mt)
#pragma unroll
            for (int r = 0; r < 4; ++r) {
                float e = __expf(st[mt][r] - mx);
                pv[mt * 4 + r] = e;
                sum += e;
            }
        sum += __shfl_xor(sum, 16);
        sum += __shfl_xor(sum, 32);
        const float rs = 1.0f / sum;
#pragma unroll
        for (int mt = 0; mt < 4; ++mt) {
            uint2 pw_;
            pw_.x = pkbf(pv[mt * 4 + 0] * rs, pv[mt * 4 + 1] * rs);
            pw_.y = pkbf(pv[mt * 4 + 2] * rs, pv[mt * 4 + 3] * rs);
            *(uint2*)(Ps + ((trow * 128 + (mt * 16 + hi * 4) * 2) ^ tswz)) = pw_;
        }
        f32x4 ot = {0.f, 0.f, 0.f, 0.f};
#pragma unroll
        for (int ks = 0; ks < 2; ++ks) {
            const int ko = (hi * 8 + ks * 32) * 2;
            short8 av = *(const short8*)(VT + (((h * 16 + lo) * 128 + ko) ^ ((lo & 7) << 4)));
            short8 bp = *(const short8*)(Ps + ((trow * 128 + ko) ^ tswz));
            ot = __builtin_amdgcn_mfma_f32_16x16x32_bf16(av, bp, ot, 0, 0, 0);
        }
        uint2 ow_;
        ow_.x = pkbf(ot[0], ot[1]); ow_.y = pkbf(ot[2], ot[3]);
        *(uint2*)(Xo + ((trow * 128 + (h * 16 + hi * 4) * 2) ^ tswz)) = ow_;
    }
    __syncthreads();  // barrier 3: Xo complete

    // ---- proj ----
    f32x4 cy[4];
#pragma unroll
    for (int mt = 0; mt < 4; ++mt) cy[mt] = (f32x4){0.f, 0.f, 0.f, 0.f};
#pragma unroll
    for (int ks = 0; ks < 2; ++ks) {
        const int koff = hi * 8 + ks * 32;
        short8 bw = *(const short8*)(projwb + (w * 16 + lo) * 64 + koff);
#pragma unroll
        for (int mt = 0; mt < 4; ++mt) {
            short8 ax = *(const short8*)(Xo + (((mt * 16 + lo) * 128 + koff * 2) ^ ((lo & 7) << 4)));
            cy[mt] = __builtin_amdgcn_mfma_f32_16x16x32_bf16(ax, bw, cy[mt], 0, 0, 0);
        }
    }
    const float pb = projb[w * 16 + lo];

    if constexpr (FUSE == 0) {
#pragma unroll
        for (int mt = 0; mt < 4; ++mt) {
#pragma unroll
            for (int r = 0; r < 4; ++r) {
                const int tok = mt * 16 + hi * 4 + r;
                const int pix = pixbase + (tok >> 3) * 128 + (tok & 7);
                dst[(size_t)pix * 64 + w * 16 + lo] = f2bf(cy[mt][r] + pb);
            }
        }
    } else {
        // fused 1x1 outconv: out[tok] = sum_ch (Y[tok][ch]) * ow[ch] + ob
        const float owv = outw[w * 16 + lo];
        float* red = (float*)VT;  // [64 tok][4 waves]
#pragma unroll
        for (int mt = 0; mt < 4; ++mt) {
#pragma unroll
            for (int r = 0; r < 4; ++r) {
                float s = (cy[mt][r] + pb) * owv;
                s += __shfl_xor(s, 1);
                s += __shfl_xor(s, 2);
                s += __shfl_xor(s, 4);
                s += __shfl_xor(s, 8);
                if (lo == 0) red[(mt * 16 + hi * 4 + r) * 4 + w] = s;
            }
        }
        __syncthreads();
        if (tid < 64) {
            const int tok = tid;
            float4 rv = *(const float4*)(red + tok * 4);
            const int pix = pixbase + (tok >> 3) * 128 + (tok & 7);
            out[pix] = (rv.x + rv.y) + (rv.z + rv.w) + outb[0];
        }
    }
}

// ---------------------------------------------------------------------------
extern "C" void kernel_launch(void* const* d_in, const int* in_sizes, int n_in,
                              void* d_out, int out_size, void* d_ws, size_t ws_size,
                              hipStream_t stream)
{
    const float* x      = (const float*)d_in[0];
    const float* cw0    = (const float*)d_in[1];
    const float* cb0    = (const float*)d_in[2];
    const float* pxw0   = (const float*)d_in[3];
    const float* pyw0   = (const float*)d_in[4];
    const float* qkvw0  = (const float*)d_in[5];
    const float* projw0 = (const float*)d_in[6];
    const float* projb0 = (const float*)d_in[7];
    const float* cw1    = (const float*)d_in[8];
    const float* cb1    = (const float*)d_in[9];
    const float* pxw1   = (const float*)d_in[10];
    const float* pyw1   = (const float*)d_in[11];
    const float* qkvw1  = (const float*)d_in[12];
    const float* projw1 = (const float*)d_in[13];
    const float* projb1 = (const float*)d_in[14];
    const float* outw   = (const float*)d_in[15];
    const float* outb   = (const float*)d_in[16];

    const size_t BUF = (size_t)16 * 128 * 128 * 64 * sizeof(float);  // 64 MB slots
    char* ws = (char*)d_ws;
    unsigned short* bufA = (unsigned short*)ws;           // h2pre0 / h2pre1
    unsigned short* bufB = (unsigned short*)(ws + BUF);   // h0
    char* wsx = ws + 2 * BUF;
    unsigned short* pwc  = (unsigned short*)(wsx);            // [0,      368640)
    float* pw0           = (float*)(wsx + 369664);            // [369664, 381184)
    unsigned short* qb0  = (unsigned short*)(wsx + 381440);   // [381440, 406016)
    unsigned short* pjb0 = (unsigned short*)(wsx + 406016);   // [406016, 414208)
    unsigned short* qb1  = (unsigned short*)(wsx + 414208);   // [414208, 438784)
    unsigned short* pjb1 = (unsigned short*)(wsx + 438784);   // [438784, 446976)

    repack_kernel<<<860, 256, 0, stream>>>(
        cw0, pxw0, pyw0, cw1, pxw1, pyw1,
        qkvw0, projw0, qkvw1, projw1,
        pwc, pw0, qb0, pjb0, qb1, pjb1);

    gates1_kernel<<<16384, 256, 0, stream>>>(x, pw0, cb0, bufA);
    attn_kernel<0><<<4096, 256, 0, stream>>>(bufA, qb0, pjb0, projb0, bufB,
                                             nullptr, nullptr, nullptr);
    gates64_kernel<<<4096, 256, 0, stream>>>(bufB, pwc, cb1, bufA);
    attn_kernel<1><<<4096, 256, 0, stream>>>(bufA, qb1, pjb1, projb1, nullptr,
                                             outw, outb, (float*)d_out);
}

// Round 17
// 290.337 us; speedup vs baseline: 1.2612x; 1.2612x over previous
//
#include <hip/hip_runtime.h>

// ConvLSTM (B=16,H=128,W=128,CIN=1,HID=64, 2 cells, h=c=0 -> f-gate dead)
// Round 17: gates64 = round-8 exact (proven 126us; BM/ch-split experiments
// all regressed). gates1 rewritten: weights+x staged in LDS (kills 1.7M
// redundant global weight gathers). attn FUSE=0 epilogue: Y staged through
// LDS -> coalesced 16B stores (was 16x scattered 2B stores/thread).
// Pipeline: repack -> gates1 -> attn<0> -> gates64 -> attn<1>(+outconv)

#define DEVFN __device__ __forceinline__

typedef __attribute__((ext_vector_type(8))) short short8;
typedef __attribute__((ext_vector_type(4))) float f32x4;

DEVFN float sigmoidf_(float z) { return 1.0f / (1.0f + __expf(-z)); }

DEVFN float tanhf_(float x) {  // fast tanh; correct limits at +-inf
    float e = __expf(2.0f * x);
    return 1.0f - 2.0f / (e + 1.0f);
}

DEVFN unsigned short f2bf(float f) {  // RNE fp32 -> bf16
    unsigned int u = __builtin_bit_cast(unsigned int, f);
    u += 0x7fffu + ((u >> 16) & 1u);
    return (unsigned short)(u >> 16);
}

DEVFN unsigned pkbf(float a, float b) {  // pack 2 fp32 -> 2 bf16 (RNE)
    return (unsigned)f2bf(a) | ((unsigned)f2bf(b) << 16);
}

// ---------------------------------------------------------------------------
// Repack.
//  pwc (bf16, 184320 el): lane-coalesced gates64 weights.
//    idx = (((g*18+kk)*4 + ng)*64 + lane)*8 + j
//    value = W[g][ch = ng*16+(lane&15)][kcol = kk*32+(lane>>4)*8+j]
//  pw0 (fp32) [5][9][64]; qkv/proj -> bf16 (row-major).
// ---------------------------------------------------------------------------
__global__ __launch_bounds__(256) void repack_kernel(
    const float* __restrict__ cw0, const float* __restrict__ pxw0, const float* __restrict__ pyw0,
    const float* __restrict__ cw1, const float* __restrict__ pxw1, const float* __restrict__ pyw1,
    const float* __restrict__ qkvw0, const float* __restrict__ projw0,
    const float* __restrict__ qkvw1, const float* __restrict__ projw1,
    unsigned short* __restrict__ pwc, float* __restrict__ pw0,
    unsigned short* __restrict__ qb0, unsigned short* __restrict__ pjb0,
    unsigned short* __restrict__ qb1, unsigned short* __restrict__ pjb1)
{
    int idx = blockIdx.x * 256 + threadIdx.x;
    if (idx < 184320) {  // 90 * 2048
        int j = idx & 7;
        int lane = (idx >> 3) & 63;
        int ng = (idx >> 9) & 3;
        int t = idx >> 11;          // g*18 + kk
        int kk = t % 18, g = t / 18;
        int c = ng * 16 + (lane & 15);
        int kcol = kk * 32 + (lane >> 4) * 8 + j;
        int pos = kcol >> 6, cin = kcol & 63;
        float v;
        if (g == 0)      v = cw1[((c      ) * 128 + cin) * 9 + pos];  // ci
        else if (g == 1) v = cw1[((128 + c) * 128 + cin) * 9 + pos];  // co
        else if (g == 2) v = cw1[((192 + c) * 128 + cin) * 9 + pos];  // cg
        else if (g == 3) v = pxw1[(c * 64 + cin) * 9 + pos];          // px
        else             v = pyw1[(c * 64 + cin) * 9 + pos];          // py
        pwc[idx] = f2bf(v);
    } else if (idx < 187200) {  // + 5*9*64
        int i2 = idx - 184320;
        int g = i2 / (9 * 64);
        int rem = i2 - g * (9 * 64);
        int pos = rem >> 6, c = rem & 63;
        float v;
        if (g == 0)      v = cw0[(c      ) * 585 + pos];
        else if (g == 1) v = cw0[(128 + c) * 585 + pos];
        else if (g == 2) v = cw0[(192 + c) * 585 + pos];
        else if (g == 3) v = pxw0[c * 9 + pos];
        else             v = pyw0[c * 9 + pos];
        pw0[i2] = v;
    } else if (idx < 187200 + 12288) {
        int i = idx - 187200;           qb0[i] = f2bf(qkvw0[i]);
    } else if (idx < 187200 + 24576) {
        int i = idx - 187200 - 12288;   qb1[i] = f2bf(qkvw1[i]);
    } else if (idx < 187200 + 24576 + 4096) {
        int i = idx - 187200 - 24576;   pjb0[i] = f2bf(projw0[i]);
    } else if (idx < 187200 + 24576 + 8192) {
        int i = idx - 187200 - 28672;   pjb1[i] = f2bf(projw1[i]);
    }
}

// ---------------------------------------------------------------------------
// Layer-0 gates (CIN=1), LDS-staged: block = 64 px (half row) x 4 ch-groups.
// pw0 (11.5KB) + x patch (3x66) staged in LDS -> weight reads are broadcast
// ds_read_b128 (was 45 redundant global gathers/thread). Math bit-identical.
// ---------------------------------------------------------------------------
__global__ __launch_bounds__(256) void gates1_kernel(
    const float* __restrict__ x, const float* __restrict__ pw,
    const float* __restrict__ cb, unsigned short* __restrict__ dst)
{
    __shared__ float wlds[5 * 9 * 64];  // 11520 B
    __shared__ float xp[3 * 66];        // 792 B

    const int tid = threadIdx.x;
    const int bid = blockIdx.x;
    const int xt = bid & 1, y = (bid >> 1) & 127, b = bid >> 8;
    const int x0 = xt * 64;

    for (int i = tid; i < 5 * 9 * 64; i += 256) wlds[i] = pw[i];
    if (tid < 198) {
        int r = tid / 66, c = tid - r * 66;
        int gy = y + r - 1, gx = x0 + c - 1;
        xp[tid] = ((unsigned)gy < 128u && (unsigned)gx < 128u)
            ? x[(b * 128 + gy) * 128 + gx] : 0.f;
    }
    __syncthreads();

    const int px = tid >> 2, cq = tid & 3;     // pixel 0..63, ch-group 0..3
    const int ch0 = cq * 16;
    float a[9];
#pragma unroll
    for (int dy = 0; dy < 3; ++dy)
#pragma unroll
        for (int dx = 0; dx < 3; ++dx)
            a[dy * 3 + dx] = xp[dy * 66 + px + dx];

    const size_t obase = (size_t)((b * 128 + y) * 128 + x0 + px) * 64 + ch0;
#pragma unroll 1
    for (int u4 = 0; u4 < 4; ++u4) {
        float acc[5][4];
#pragma unroll
        for (int g = 0; g < 5; ++g)
#pragma unroll
            for (int u = 0; u < 4; ++u) acc[g][u] = 0.f;
#pragma unroll
        for (int pos = 0; pos < 9; ++pos) {
            const float av = a[pos];
#pragma unroll
            for (int g = 0; g < 5; ++g) {
                const float4 w4 = *(const float4*)(wlds + (g * 9 + pos) * 64 + ch0 + 4 * u4);
                acc[g][0] = fmaf(av, w4.x, acc[g][0]);
                acc[g][1] = fmaf(av, w4.y, acc[g][1]);
                acc[g][2] = fmaf(av, w4.z, acc[g][2]);
                acc[g][3] = fmaf(av, w4.w, acc[g][3]);
            }
        }
        float hv[4];
#pragma unroll
        for (int u = 0; u < 4; ++u) {
            const int ch = ch0 + 4 * u4 + u;
            float ci = acc[0][u] + cb[ch];
            float co = acc[1][u] + cb[128 + ch];
            float cg = acc[2][u] + cb[192 + ch];
            float iv = sigmoidf_(ci + acc[3][u]);
            float ov = sigmoidf_(co + acc[4][u]);
            float gv = tanhf_(cg + acc[4][u]);
            hv[u] = ov * tanhf_(iv * gv);
        }
        uint2 o;
        o.x = pkbf(hv[0], hv[1]);
        o.y = pkbf(hv[2], hv[3]);
        *(uint2*)(dst + obase + 4 * u4) = o;
    }
}

// ---------------------------------------------------------------------------
// Layer-1 gates: bf16 MFMA implicit GEMM (round-8 exact: BM=64, 256 thr,
// lane-coalesced weights, launch_bounds(256,2)). Proven 126us.
// ---------------------------------------------------------------------------
__global__ __launch_bounds__(256, 2) void gates64_kernel(
    const unsigned short* __restrict__ src, const unsigned short* __restrict__ wtc,
    const float* __restrict__ cb, unsigned short* __restrict__ dst)
{
    __shared__ unsigned short lds[3 * 66 * 64];
    char* const sbase = (char*)lds;

    const int tid = threadIdx.x;
    const int bid = blockIdx.x;
    const int xt = bid & 1, y = (bid >> 1) & 127, b = bid >> 8;
    const int x0 = xt * 64;

    for (int i4 = tid; i4 < 3 * 66 * 8; i4 += 256) {
        int r = i4 / (66 * 8);
        int rem = i4 - r * (66 * 8);
        int xx = rem >> 3, c8 = rem & 7;
        int gy = y + r - 1, gx = x0 + xx - 1;
        uint4 wv = make_uint4(0, 0, 0, 0);
        if ((unsigned)gy < 128u && (unsigned)gx < 128u)
            wv = *(const uint4*)(src + (((size_t)(b * 128 + gy) * 128 + gx) * 64 + c8 * 8));
        int addr = ((r * 66 + xx) * 128 + c8 * 16) ^ ((xx & 7) << 4);
        *(uint4*)(sbase + addr) = wv;
    }
    __syncthreads();

    const int lane = tid & 63;
    const int wv_ = tid >> 6;
    const int r0 = lane & 15;
    const int hi = lane >> 4;
    const int wch = wv_ * 16 + r0;

    const unsigned short* wbase = wtc + (size_t)(wv_ * 64 + lane) * 8;

    f32x4 acc[4][5];
#pragma unroll
    for (int mt = 0; mt < 4; ++mt)
#pragma unroll
        for (int g = 0; g < 5; ++g) acc[mt][g] = (f32x4){0.f, 0.f, 0.f, 0.f};

#pragma unroll
    for (int kk = 0; kk < 18; ++kk) {
        const int pos = kk >> 1, dy = pos / 3, dx = pos % 3, chalf = kk & 1;
        const int swz = (((r0 + dx) & 7) << 4);
        short8 bfr[5];
#pragma unroll
        for (int g = 0; g < 5; ++g)
            bfr[g] = *(const short8*)(wbase + (g * 18 + kk) * 2048);
        short8 afr[4];
#pragma unroll
        for (int mt = 0; mt < 4; ++mt) {
            const int row = dy * 66 + mt * 16 + r0 + dx;
            const int addr = (row * 128 + chalf * 64 + hi * 16) ^ swz;
            afr[mt] = *(const short8*)(sbase + addr);
        }
#pragma unroll
        for (int mt = 0; mt < 4; ++mt)
#pragma unroll
            for (int g = 0; g < 5; ++g)
                acc[mt][g] = __builtin_amdgcn_mfma_f32_16x16x32_bf16(
                    afr[mt], bfr[g], acc[mt][g], 0, 0, 0);
    }

    const float bci = cb[wch], bco = cb[128 + wch], bcg = cb[192 + wch];
    const int rowbase = (b * 128 + y) * 128 + x0;
#pragma unroll
    for (int mt = 0; mt < 4; ++mt) {
#pragma unroll
        for (int rg = 0; rg < 4; ++rg) {
            const int px_i = mt * 16 + hi * 4 + rg;
            float ci = acc[mt][0][rg] + bci;
            float co = acc[mt][1][rg] + bco;
            float cg = acc[mt][2][rg] + bcg;
            float pxv = acc[mt][3][rg];
            float pyv = acc[mt][4][rg];
            float iv = sigmoidf_(ci + pxv);
            float ov = sigmoidf_(co + pyv);
            float gv = tanhf_(cg + pyv);
            dst[(size_t)(rowbase + px_i) * 64 + wch] = f2bf(ov * tanhf_(iv * gv));
        }
    }
}

// ---------------------------------------------------------------------------
// Window attention v5 (3 barriers; Ps overlays dead Xs -> 40KB LDS).
// FUSE=0: Y staged through LDS -> coalesced 16B global stores.
// FUSE=1: fold the 1x1 outconv into the epilogue (h1 never hits HBM).
// ---------------------------------------------------------------------------
template <int FUSE>
__global__ __launch_bounds__(256, 3) void attn_kernel(
    const unsigned short* __restrict__ src,    // NHWC bf16 [16,128,128,64]
    const unsigned short* __restrict__ qkvwb,  // [192][64] bf16
    const unsigned short* __restrict__ projwb, // [64][64] bf16
    const float* __restrict__ projb,           // [64]
    unsigned short* __restrict__ dst,          // NHWC bf16 (FUSE=0)
    const float* __restrict__ outw,            // [64] (FUSE=1)
    const float* __restrict__ outb,            // [1]  (FUSE=1)
    float* __restrict__ out)                   // [16,128,128,1] (FUSE=1)
{
    __shared__ char sm[40960];
    char* const Xs = sm;             // [64 tok][128B] swz; DEAD after barrier 2
    char* const Ps = sm;             //   -> [64 q][64key*2B] swz; then Y stage
    char* const Xo = sm + 8192;      // [64 tok][128B] swz
    char* const Qa = sm + 16384;     // [64 tok][64d*2B] swz
    char* const Ka = sm + 24576;     // [64 tok][64d*2B] swz
    char* const VT = sm + 32768;     // [64 d][64tok*2B] swz; reused as red[64][4]

    const int tid = threadIdx.x;
    const int lane = tid & 63;
    const int w = __builtin_amdgcn_readfirstlane(tid >> 6);
    const int lo = lane & 15, hi = lane >> 4;
    const int wid = blockIdx.x;
    const int b = wid >> 8, rem = wid & 255, wy = rem >> 4, wx = rem & 15;
    const int pixbase = (b * 128 + wy * 8) * 128 + wx * 8;

    // ---- stage X: bf16 copy, swizzled ----
    {
        const int t = tid >> 2, c0 = (tid & 3) * 16;
        const int pix = pixbase + (t >> 3) * 128 + (t & 7);
        const uint4* sp = (const uint4*)(src + (size_t)pix * 64 + c0);
        uint4 w0 = sp[0], w1 = sp[1];
        const int a = t * 128 + c0 * 2, sz = (t & 7) << 4;
        *(uint4*)(Xs + (a ^ sz)) = w0;
        *(uint4*)(Xs + ((a + 16) ^ sz)) = w1;
    }
    __syncthreads();  // barrier 1: Xs complete

    const int trow = w * 16 + lo;
    const int tswz = (lo & 7) << 4;

    // ---- QKV for ALL heads (wave w covers its token slice) ----
#pragma unroll
    for (int h = 0; h < 4; ++h) {
        f32x4 cq = {0.f, 0.f, 0.f, 0.f}, ck = cq, cv = cq;
#pragma unroll
        for (int ks = 0; ks < 2; ++ks) {
            const int koff = hi * 8 + ks * 32;
            short8 xb = *(const short8*)(Xs + ((trow * 128 + koff * 2) ^ tswz));
            short8 aq = *(const short8*)(qkvwb + (h * 16 + lo) * 64 + koff);
            short8 ak = *(const short8*)(qkvwb + (64 + h * 16 + lo) * 64 + koff);
            short8 bv = *(const short8*)(qkvwb + (128 + h * 16 + lo) * 64 + koff);
            cq = __builtin_amdgcn_mfma_f32_16x16x32_bf16(aq, xb, cq, 0, 0, 0);
            ck = __builtin_amdgcn_mfma_f32_16x16x32_bf16(ak, xb, ck, 0, 0, 0);
            cv = __builtin_amdgcn_mfma_f32_16x16x32_bf16(xb, bv, cv, 0, 0, 0);
        }
        uint2 qw, kw, vw;
        qw.x = pkbf(cq[0] * 0.125f, cq[1] * 0.125f);
        qw.y = pkbf(cq[2] * 0.125f, cq[3] * 0.125f);
        kw.x = pkbf(ck[0], ck[1]); kw.y = pkbf(ck[2], ck[3]);
        vw.x = pkbf(cv[0], cv[1]); vw.y = pkbf(cv[2], cv[3]);
        *(uint2*)(Qa + ((trow * 128 + (h * 16 + hi * 4) * 2) ^ tswz)) = qw;
        *(uint2*)(Ka + ((trow * 128 + (h * 16 + hi * 4) * 2) ^ tswz)) = kw;
        *(uint2*)(VT + (((h * 16 + lo) * 128 + (w * 16 + hi * 4) * 2) ^ ((lo & 7) << 4))) = vw;
    }
    __syncthreads();  // barrier 2: Qa/Ka/VT complete; Xs now dead -> Ps

    // ---- per head: scores + softmax + PV (wave-private P/Xo rows) ----
#pragma unroll 1
    for (int h = 0; h < 4; ++h) {
        const int hb = h * 32;
        short8 bq = *(const short8*)(Qa + ((trow * 128 + hb + (hi & 1) * 16) ^ tswz));
        f32x4 st[4];
#pragma unroll
        for (int mt = 0; mt < 4; ++mt) {
            short8 ak2 = *(const short8*)(Ka + (((mt * 16 + lo) * 128 + hb + (hi & 1) * 16) ^ ((lo & 7) << 4)));
            f32x4 z = {0.f, 0.f, 0.f, 0.f};
            st[mt] = __builtin_amdgcn_mfma_f32_16x16x32_bf16(ak2, bq, z, 0, 0, 0);
        }
        float mx = -1e30f;
#pragma unroll
        for (int mt = 0; mt < 4; ++mt)
#pragma unroll
            for (int r = 0; r < 4; ++r) mx = fmaxf(mx, st[mt][r]);
        mx = fmaxf(mx, __shfl_xor(mx, 16));
        mx = fmaxf(mx, __shfl_xor(mx, 32));
        float pv[16];
        float sum = 0.f;
#pragma unroll
        for (int mt = 0; mt < 4; ++mt)
#pragma unroll
            for (int r = 0; r < 4; ++r) {
                float e = __expf(st[mt][r] - mx);
                pv[mt * 4 + r] = e;
                sum += e;
            }
        sum += __shfl_xor(sum, 16);
        sum += __shfl_xor(sum, 32);
        const float rs = 1.0f / sum;
#pragma unroll
        for (int mt = 0; mt < 4; ++mt) {
            uint2 pw_;
            pw_.x = pkbf(pv[mt * 4 + 0] * rs, pv[mt * 4 + 1] * rs);
            pw_.y = pkbf(pv[mt * 4 + 2] * rs, pv[mt * 4 + 3] * rs);
            *(uint2*)(Ps + ((trow * 128 + (mt * 16 + hi * 4) * 2) ^ tswz)) = pw_;
        }
        f32x4 ot = {0.f, 0.f, 0.f, 0.f};
#pragma unroll
        for (int ks = 0; ks < 2; ++ks) {
            const int ko = (hi * 8 + ks * 32) * 2;
            short8 av = *(const short8*)(VT + (((h * 16 + lo) * 128 + ko) ^ ((lo & 7) << 4)));
            short8 bp = *(const short8*)(Ps + ((trow * 128 + ko) ^ tswz));
            ot = __builtin_amdgcn_mfma_f32_16x16x32_bf16(av, bp, ot, 0, 0, 0);
        }
        uint2 ow_;
        ow_.x = pkbf(ot[0], ot[1]); ow_.y = pkbf(ot[2], ot[3]);
        *(uint2*)(Xo + ((trow * 128 + (h * 16 + hi * 4) * 2) ^ tswz)) = ow_;
    }
    __syncthreads();  // barrier 3: Xo complete; Ps region dead again

    // ---- proj ----
    f32x4 cy[4];
#pragma unroll
    for (int mt = 0; mt < 4; ++mt) cy[mt] = (f32x4){0.f, 0.f, 0.f, 0.f};
#pragma unroll
    for (int ks = 0; ks < 2; ++ks) {
        const int koff = hi * 8 + ks * 32;
        short8 bw = *(const short8*)(projwb + (w * 16 + lo) * 64 + koff);
#pragma unroll
        for (int mt = 0; mt < 4; ++mt) {
            short8 ax = *(const short8*)(Xo + (((mt * 16 + lo) * 128 + koff * 2) ^ ((lo & 7) << 4)));
            cy[mt] = __builtin_amdgcn_mfma_f32_16x16x32_bf16(ax, bw, cy[mt], 0, 0, 0);
        }
    }
    const float pb = projb[w * 16 + lo];

    if constexpr (FUSE == 0) {
        // stage Y (bf16, linear [tok][64ch]) in Ps region -> coalesced stores
        unsigned short* Y = (unsigned short*)Ps;
#pragma unroll
        for (int mt = 0; mt < 4; ++mt) {
#pragma unroll
            for (int r = 0; r < 4; ++r) {
                const int tok = mt * 16 + hi * 4 + r;
                Y[tok * 64 + w * 16 + lo] = f2bf(cy[mt][r] + pb);
            }
        }
        __syncthreads();  // barrier 4: Y complete
        {
            const int t = tid >> 2, c0 = (tid & 3) * 16;
            const int pix = pixbase + (t >> 3) * 128 + (t & 7);
            const uint4* yp = (const uint4*)(Y + t * 64 + c0);
            uint4* dp = (uint4*)(dst + (size_t)pix * 64 + c0);
            dp[0] = yp[0];
            dp[1] = yp[1];
        }
    } else {
        // fused 1x1 outconv: out[tok] = sum_ch (Y[tok][ch]) * ow[ch] + ob
        const float owv = outw[w * 16 + lo];
        float* red = (float*)VT;  // [64 tok][4 waves]
#pragma unroll
        for (int mt = 0; mt < 4; ++mt) {
#pragma unroll
            for (int r = 0; r < 4; ++r) {
                float s = (cy[mt][r] + pb) * owv;
                s += __shfl_xor(s, 1);
                s += __shfl_xor(s, 2);
                s += __shfl_xor(s, 4);
                s += __shfl_xor(s, 8);
                if (lo == 0) red[(mt * 16 + hi * 4 + r) * 4 + w] = s;
            }
        }
        __syncthreads();
        if (tid < 64) {
            const int tok = tid;
            float4 rv = *(const float4*)(red + tok * 4);
            const int pix = pixbase + (tok >> 3) * 128 + (tok & 7);
            out[pix] = (rv.x + rv.y) + (rv.z + rv.w) + outb[0];
        }
    }
}

// ---------------------------------------------------------------------------
extern "C" void kernel_launch(void* const* d_in, const int* in_sizes, int n_in,
                              void* d_out, int out_size, void* d_ws, size_t ws_size,
                              hipStream_t stream)
{
    const float* x      = (const float*)d_in[0];
    const float* cw0    = (const float*)d_in[1];
    const float* cb0    = (const float*)d_in[2];
    const float* pxw0   = (const float*)d_in[3];
    const float* pyw0   = (const float*)d_in[4];
    const float* qkvw0  = (const float*)d_in[5];
    const float* projw0 = (const float*)d_in[6];
    const float* projb0 = (const float*)d_in[7];
    const float* cw1    = (const float*)d_in[8];
    const float* cb1    = (const float*)d_in[9];
    const float* pxw1   = (const float*)d_in[10];
    const float* pyw1   = (const float*)d_in[11];
    const float* qkvw1  = (const float*)d_in[12];
    const float* projw1 = (const float*)d_in[13];
    const float* projb1 = (const float*)d_in[14];
    const float* outw   = (const float*)d_in[15];
    const float* outb   = (const float*)d_in[16];

    const size_t BUF = (size_t)16 * 128 * 128 * 64 * sizeof(float);  // 64 MB slots
    char* ws = (char*)d_ws;
    unsigned short* bufA = (unsigned short*)ws;           // h2pre0 / h2pre1
    unsigned short* bufB = (unsigned short*)(ws + BUF);   // h0
    char* wsx = ws + 2 * BUF;
    unsigned short* pwc  = (unsigned short*)(wsx);            // [0,      368640)
    float* pw0           = (float*)(wsx + 369664);            // [369664, 381184)
    unsigned short* qb0  = (unsigned short*)(wsx + 381440);   // [381440, 406016)
    unsigned short* pjb0 = (unsigned short*)(wsx + 406016);   // [406016, 414208)
    unsigned short* qb1  = (unsigned short*)(wsx + 414208);   // [414208, 438784)
    unsigned short* pjb1 = (unsigned short*)(wsx + 438784);   // [438784, 446976)

    repack_kernel<<<860, 256, 0, stream>>>(
        cw0, pxw0, pyw0, cw1, pxw1, pyw1,
        qkvw0, projw0, qkvw1, projw1,
        pwc, pw0, qb0, pjb0, qb1, pjb1);

    gates1_kernel<<<4096, 256, 0, stream>>>(x, pw0, cb0, bufA);
    attn_kernel<0><<<4096, 256, 0, stream>>>(bufA, qb0, pjb0, projb0, bufB,
                                             nullptr, nullptr, nullptr);
    gates64_kernel<<<4096, 256, 0, stream>>>(bufB, pwc, cb1, bufA);
    attn_kernel<1><<<4096, 256, 0, stream>>>(bufA, qb1, pjb1, projb1, nullptr,
                                             outw, outb, (float*)d_out);
}

// Round 18
// 290.002 us; speedup vs baseline: 1.2627x; 1.0012x over previous
//
#include <hip/hip_runtime.h>

// ConvLSTM (B=16,H=128,W=128,CIN=1,HID=64, 2 cells, h=c=0 -> f-gate dead)
// Round 17: gates64 = round-8 exact (proven 126us; BM/ch-split experiments
// all regressed). gates1 rewritten: weights+x staged in LDS (kills 1.7M
// redundant global weight gathers). attn FUSE=0 epilogue: Y staged through
// LDS -> coalesced 16B stores (was 16x scattered 2B stores/thread).
// Pipeline: repack -> gates1 -> attn<0> -> gates64 -> attn<1>(+outconv)

#define DEVFN __device__ __forceinline__

typedef __attribute__((ext_vector_type(8))) short short8;
typedef __attribute__((ext_vector_type(4))) float f32x4;

DEVFN float sigmoidf_(float z) { return 1.0f / (1.0f + __expf(-z)); }

DEVFN float tanhf_(float x) {  // fast tanh; correct limits at +-inf
    float e = __expf(2.0f * x);
    return 1.0f - 2.0f / (e + 1.0f);
}

DEVFN unsigned short f2bf(float f) {  // RNE fp32 -> bf16
    unsigned int u = __builtin_bit_cast(unsigned int, f);
    u += 0x7fffu + ((u >> 16) & 1u);
    return (unsigned short)(u >> 16);
}

DEVFN unsigned pkbf(float a, float b) {  // pack 2 fp32 -> 2 bf16 (RNE)
    return (unsigned)f2bf(a) | ((unsigned)f2bf(b) << 16);
}

// ---------------------------------------------------------------------------
// Repack.
//  pwc (bf16, 184320 el): lane-coalesced gates64 weights.
//    idx = (((g*18+kk)*4 + ng)*64 + lane)*8 + j
//    value = W[g][ch = ng*16+(lane&15)][kcol = kk*32+(lane>>4)*8+j]
//  pw0 (fp32) [5][9][64]; qkv/proj -> bf16 (row-major).
// ---------------------------------------------------------------------------
__global__ __launch_bounds__(256) void repack_kernel(
    const float* __restrict__ cw0, const float* __restrict__ pxw0, const float* __restrict__ pyw0,
    const float* __restrict__ cw1, const float* __restrict__ pxw1, const float* __restrict__ pyw1,
    const float* __restrict__ qkvw0, const float* __restrict__ projw0,
    const float* __restrict__ qkvw1, const float* __restrict__ projw1,
    unsigned short* __restrict__ pwc, float* __restrict__ pw0,
    unsigned short* __restrict__ qb0, unsigned short* __restrict__ pjb0,
    unsigned short* __restrict__ qb1, unsigned short* __restrict__ pjb1)
{
    int idx = blockIdx.x * 256 + threadIdx.x;
    if (idx < 184320) {  // 90 * 2048
        int j = idx & 7;
        int lane = (idx >> 3) & 63;
        int ng = (idx >> 9) & 3;
        int t = idx >> 11;          // g*18 + kk
        int kk = t % 18, g = t / 18;
        int c = ng * 16 + (lane & 15);
        int kcol = kk * 32 + (lane >> 4) * 8 + j;
        int pos = kcol >> 6, cin = kcol & 63;
        float v;
        if (g == 0)      v = cw1[((c      ) * 128 + cin) * 9 + pos];  // ci
        else if (g == 1) v = cw1[((128 + c) * 128 + cin) * 9 + pos];  // co
        else if (g == 2) v = cw1[((192 + c) * 128 + cin) * 9 + pos];  // cg
        else if (g == 3) v = pxw1[(c * 64 + cin) * 9 + pos];          // px
        else             v = pyw1[(c * 64 + cin) * 9 + pos];          // py
        pwc[idx] = f2bf(v);
    } else if (idx < 187200) {  // + 5*9*64
        int i2 = idx - 184320;
        int g = i2 / (9 * 64);
        int rem = i2 - g * (9 * 64);
        int pos = rem >> 6, c = rem & 63;
        float v;
        if (g == 0)      v = cw0[(c      ) * 585 + pos];
        else if (g == 1) v = cw0[(128 + c) * 585 + pos];
        else if (g == 2) v = cw0[(192 + c) * 585 + pos];
        else if (g == 3) v = pxw0[c * 9 + pos];
        else             v = pyw0[c * 9 + pos];
        pw0[i2] = v;
    } else if (idx < 187200 + 12288) {
        int i = idx - 187200;           qb0[i] = f2bf(qkvw0[i]);
    } else if (idx < 187200 + 24576) {
        int i = idx - 187200 - 12288;   qb1[i] = f2bf(qkvw1[i]);
    } else if (idx < 187200 + 24576 + 4096) {
        int i = idx - 187200 - 24576;   pjb0[i] = f2bf(projw0[i]);
    } else if (idx < 187200 + 24576 + 8192) {
        int i = idx - 187200 - 28672;   pjb1[i] = f2bf(projw1[i]);
    }
}

// ---------------------------------------------------------------------------
// Layer-0 gates (CIN=1), LDS-staged: block = 64 px (half row) x 4 ch-groups.
// pw0 (11.5KB) + x patch (3x66) staged in LDS -> weight reads are broadcast
// ds_read_b128 (was 45 redundant global gathers/thread). Math bit-identical.
// ---------------------------------------------------------------------------
__global__ __launch_bounds__(256) void gates1_kernel(
    const float* __restrict__ x, const float* __restrict__ pw,
    const float* __restrict__ cb, unsigned short* __restrict__ dst)
{
    __shared__ float wlds[5 * 9 * 64];  // 11520 B
    __shared__ float xp[3 * 66];        // 792 B

    const int tid = threadIdx.x;
    const int bid = blockIdx.x;
    const int xt = bid & 1, y = (bid >> 1) & 127, b = bid >> 8;
    const int x0 = xt * 64;

    for (int i = tid; i < 5 * 9 * 64; i += 256) wlds[i] = pw[i];
    if (tid < 198) {
        int r = tid / 66, c = tid - r * 66;
        int gy = y + r - 1, gx = x0 + c - 1;
        xp[tid] = ((unsigned)gy < 128u && (unsigned)gx < 128u)
            ? x[(b * 128 + gy) * 128 + gx] : 0.f;
    }
    __syncthreads();

    const int px = tid >> 2, cq = tid & 3;     // pixel 0..63, ch-group 0..3
    const int ch0 = cq * 16;
    float a[9];
#pragma unroll
    for (int dy = 0; dy < 3; ++dy)
#pragma unroll
        for (int dx = 0; dx < 3; ++dx)
            a[dy * 3 + dx] = xp[dy * 66 + px + dx];

    const size_t obase = (size_t)((b * 128 + y) * 128 + x0 + px) * 64 + ch0;
#pragma unroll 1
    for (int u4 = 0; u4 < 4; ++u4) {
        float acc[5][4];
#pragma unroll
        for (int g = 0; g < 5; ++g)
#pragma unroll
            for (int u = 0; u < 4; ++u) acc[g][u] = 0.f;
#pragma unroll
        for (int pos = 0; pos < 9; ++pos) {
            const float av = a[pos];
#pragma unroll
            for (int g = 0; g < 5; ++g) {
                const float4 w4 = *(const float4*)(wlds + (g * 9 + pos) * 64 + ch0 + 4 * u4);
                acc[g][0] = fmaf(av, w4.x, acc[g][0]);
                acc[g][1] = fmaf(av, w4.y, acc[g][1]);
                acc[g][2] = fmaf(av, w4.z, acc[g][2]);
                acc[g][3] = fmaf(av, w4.w, acc[g][3]);
            }
        }
        float hv[4];
#pragma unroll
        for (int u = 0; u < 4; ++u) {
            const int ch = ch0 + 4 * u4 + u;
            float ci = acc[0][u] + cb[ch];
            float co = acc[1][u] + cb[128 + ch];
            float cg = acc[2][u] + cb[192 + ch];
            float iv = sigmoidf_(ci + acc[3][u]);
            float ov = sigmoidf_(co + acc[4][u]);
            float gv = tanhf_(cg + acc[4][u]);
            hv[u] = ov * tanhf_(iv * gv);
        }
        uint2 o;
        o.x = pkbf(hv[0], hv[1]);
        o.y = pkbf(hv[2], hv[3]);
        *(uint2*)(dst + obase + 4 * u4) = o;
    }
}

// ---------------------------------------------------------------------------
// Layer-1 gates: bf16 MFMA implicit GEMM (round-8 exact: BM=64, 256 thr,
// lane-coalesced weights, launch_bounds(256,2)). Proven 126us.
// ---------------------------------------------------------------------------
__global__ __launch_bounds__(256, 2) void gates64_kernel(
    const unsigned short* __restrict__ src, const unsigned short* __restrict__ wtc,
    const float* __restrict__ cb, unsigned short* __restrict__ dst)
{
    __shared__ unsigned short lds[3 * 66 * 64];
    char* const sbase = (char*)lds;

    const int tid = threadIdx.x;
    const int bid = blockIdx.x;
    const int xt = bid & 1, y = (bid >> 1) & 127, b = bid >> 8;
    const int x0 = xt * 64;

    for (int i4 = tid; i4 < 3 * 66 * 8; i4 += 256) {
        int r = i4 / (66 * 8);
        int rem = i4 - r * (66 * 8);
        int xx = rem >> 3, c8 = rem & 7;
        int gy = y + r - 1, gx = x0 + xx - 1;
        uint4 wv = make_uint4(0, 0, 0, 0);
        if ((unsigned)gy < 128u && (unsigned)gx < 128u)
            wv = *(const uint4*)(src + (((size_t)(b * 128 + gy) * 128 + gx) * 64 + c8 * 8));
        int addr = ((r * 66 + xx) * 128 + c8 * 16) ^ ((xx & 7) << 4);
        *(uint4*)(sbase + addr) = wv;
    }
    __syncthreads();

    const int lane = tid & 63;
    const int wv_ = tid >> 6;
    const int r0 = lane & 15;
    const int hi = lane >> 4;
    const int wch = wv_ * 16 + r0;

    const unsigned short* wbase = wtc + (size_t)(wv_ * 64 + lane) * 8;

    f32x4 acc[4][5];
#pragma unroll
    for (int mt = 0; mt < 4; ++mt)
#pragma unroll
        for (int g = 0; g < 5; ++g) acc[mt][g] = (f32x4){0.f, 0.f, 0.f, 0.f};

#pragma unroll
    for (int kk = 0; kk < 18; ++kk) {
        const int pos = kk >> 1, dy = pos / 3, dx = pos % 3, chalf = kk & 1;
        const int swz = (((r0 + dx) & 7) << 4);
        short8 bfr[5];
#pragma unroll
        for (int g = 0; g < 5; ++g)
            bfr[g] = *(const short8*)(wbase + (g * 18 + kk) * 2048);
        short8 afr[4];
#pragma unroll
        for (int mt = 0; mt < 4; ++mt) {
            const int row = dy * 66 + mt * 16 + r0 + dx;
            const int addr = (row * 128 + chalf * 64 + hi * 16) ^ swz;
            afr[mt] = *(const short8*)(sbase + addr);
        }
#pragma unroll
        for (int mt = 0; mt < 4; ++mt)
#pragma unroll
            for (int g = 0; g < 5; ++g)
                acc[mt][g] = __builtin_amdgcn_mfma_f32_16x16x32_bf16(
                    afr[mt], bfr[g], acc[mt][g], 0, 0, 0);
    }

    const float bci = cb[wch], bco = cb[128 + wch], bcg = cb[192 + wch];
    const int rowbase = (b * 128 + y) * 128 + x0;
#pragma unroll
    for (int mt = 0; mt < 4; ++mt) {
#pragma unroll
        for (int rg = 0; rg < 4; ++rg) {
            const int px_i = mt * 16 + hi * 4 + rg;
            float ci = acc[mt][0][rg] + bci;
            float co = acc[mt][1][rg] + bco;
            float cg = acc[mt][2][rg] + bcg;
            float pxv = acc[mt][3][rg];
            float pyv = acc[mt][4][rg];
            float iv = sigmoidf_(ci + pxv);
            float ov = sigmoidf_(co + pyv);
            float gv = tanhf_(cg + pyv);
            dst[(size_t)(rowbase + px_i) * 64 + wch] = f2bf(ov * tanhf_(iv * gv));
        }
    }
}

// ---------------------------------------------------------------------------
// Window attention v5 (3 barriers; Ps overlays dead Xs -> 40KB LDS).
// FUSE=0: Y staged through LDS -> coalesced 16B global stores.
// FUSE=1: fold the 1x1 outconv into the epilogue (h1 never hits HBM).
// ---------------------------------------------------------------------------
template <int FUSE>
__global__ __launch_bounds__(256, 3) void attn_kernel(
    const unsigned short* __restrict__ src,    // NHWC bf16 [16,128,128,64]
    const unsigned short* __restrict__ qkvwb,  // [192][64] bf16
    const unsigned short* __restrict__ projwb, // [64][64] bf16
    const float* __restrict__ projb,           // [64]
    unsigned short* __restrict__ dst,          // NHWC bf16 (FUSE=0)
    const float* __restrict__ outw,            // [64] (FUSE=1)
    const float* __restrict__ outb,            // [1]  (FUSE=1)
    float* __restrict__ out)                   // [16,128,128,1] (FUSE=1)
{
    __shared__ char sm[40960];
    char* const Xs = sm;             // [64 tok][128B] swz; DEAD after barrier 2
    char* const Ps = sm;             //   -> [64 q][64key*2B] swz; then Y stage
    char* const Xo = sm + 8192;      // [64 tok][128B] swz
    char* const Qa = sm + 16384;     // [64 tok][64d*2B] swz
    char* const Ka = sm + 24576;     // [64 tok][64d*2B] swz
    char* const VT = sm + 32768;     // [64 d][64tok*2B] swz; reused as red[64][4]

    const int tid = threadIdx.x;
    const int lane = tid & 63;
    const int w = __builtin_amdgcn_readfirstlane(tid >> 6);
    const int lo = lane & 15, hi = lane >> 4;
    const int wid = blockIdx.x;
    const int b = wid >> 8, rem = wid & 255, wy = rem >> 4, wx = rem & 15;
    const int pixbase = (b * 128 + wy * 8) * 128 + wx * 8;

    // ---- stage X: bf16 copy, swizzled ----
    {
        const int t = tid >> 2, c0 = (tid & 3) * 16;
        const int pix = pixbase + (t >> 3) * 128 + (t & 7);
        const uint4* sp = (const uint4*)(src + (size_t)pix * 64 + c0);
        uint4 w0 = sp[0], w1 = sp[1];
        const int a = t * 128 + c0 * 2, sz = (t & 7) << 4;
        *(uint4*)(Xs + (a ^ sz)) = w0;
        *(uint4*)(Xs + ((a + 16) ^ sz)) = w1;
    }
    __syncthreads();  // barrier 1: Xs complete

    const int trow = w * 16 + lo;
    const int tswz = (lo & 7) << 4;

    // ---- QKV for ALL heads (wave w covers its token slice) ----
#pragma unroll
    for (int h = 0; h < 4; ++h) {
        f32x4 cq = {0.f, 0.f, 0.f, 0.f}, ck = cq, cv = cq;
#pragma unroll
        for (int ks = 0; ks < 2; ++ks) {
            const int koff = hi * 8 + ks * 32;
            short8 xb = *(const short8*)(Xs + ((trow * 128 + koff * 2) ^ tswz));
            short8 aq = *(const short8*)(qkvwb + (h * 16 + lo) * 64 + koff);
            short8 ak = *(const short8*)(qkvwb + (64 + h * 16 + lo) * 64 + koff);
            short8 bv = *(const short8*)(qkvwb + (128 + h * 16 + lo) * 64 + koff);
            cq = __builtin_amdgcn_mfma_f32_16x16x32_bf16(aq, xb, cq, 0, 0, 0);
            ck = __builtin_amdgcn_mfma_f32_16x16x32_bf16(ak, xb, ck, 0, 0, 0);
            cv = __builtin_amdgcn_mfma_f32_16x16x32_bf16(xb, bv, cv, 0, 0, 0);
        }
        uint2 qw, kw, vw;
        qw.x = pkbf(cq[0] * 0.125f, cq[1] * 0.125f);
        qw.y = pkbf(cq[2] * 0.125f, cq[3] * 0.125f);
        kw.x = pkbf(ck[0], ck[1]); kw.y = pkbf(ck[2], ck[3]);
        vw.x = pkbf(cv[0], cv[1]); vw.y = pkbf(cv[2], cv[3]);
        *(uint2*)(Qa + ((trow * 128 + (h * 16 + hi * 4) * 2) ^ tswz)) = qw;
        *(uint2*)(Ka + ((trow * 128 + (h * 16 + hi * 4) * 2) ^ tswz)) = kw;
        *(uint2*)(VT + (((h * 16 + lo) * 128 + (w * 16 + hi * 4) * 2) ^ ((lo & 7) << 4))) = vw;
    }
    __syncthreads();  // barrier 2: Qa/Ka/VT complete; Xs now dead -> Ps

    // ---- per head: scores + softmax + PV (wave-private P/Xo rows) ----
#pragma unroll 1
    for (int h = 0; h < 4; ++h) {
        const int hb = h * 32;
        short8 bq = *(const short8*)(Qa + ((trow * 128 + hb + (hi & 1) * 16) ^ tswz));
        f32x4 st[4];
#pragma unroll
        for (int mt = 0; mt < 4; ++mt) {
            short8 ak2 = *(const short8*)(Ka + (((mt * 16 + lo) * 128 + hb + (hi & 1) * 16) ^ ((lo & 7) << 4)));
            f32x4 z = {0.f, 0.f, 0.f, 0.f};
            st[mt] = __builtin_amdgcn_mfma_f32_16x16x32_bf16(ak2, bq, z, 0, 0, 0);
        }
        float mx = -1e30f;
#pragma unroll
        for (int mt = 0; mt < 4; ++mt)
#pragma unroll
            for (int r = 0; r < 4; ++r) mx = fmaxf(mx, st[mt][r]);
        mx = fmaxf(mx, __shfl_xor(mx, 16));
        mx = fmaxf(mx, __shfl_xor(mx, 32));
        float pv[16];
        float sum = 0.f;
#pragma unroll
        for (int mt = 0; mt < 4; ++mt)
#pragma unroll
            for (int r = 0; r < 4; ++r) {
                float e = __expf(st[mt][r] - mx);
                pv[mt * 4 + r] = e;
                sum += e;
            }
        sum += __shfl_xor(sum, 16);
        sum += __shfl_xor(sum, 32);
        const float rs = 1.0f / sum;
#pragma unroll
        for (int mt = 0; mt < 4; ++mt) {
            uint2 pw_;
            pw_.x = pkbf(pv[mt * 4 + 0] * rs, pv[mt * 4 + 1] * rs);
            pw_.y = pkbf(pv[mt * 4 + 2] * rs, pv[mt * 4 + 3] * rs);
            *(uint2*)(Ps + ((trow * 128 + (mt * 16 + hi * 4) * 2) ^ tswz)) = pw_;
        }
        f32x4 ot = {0.f, 0.f, 0.f, 0.f};
#pragma unroll
        for (int ks = 0; ks < 2; ++ks) {
            const int ko = (hi * 8 + ks * 32) * 2;
            short8 av = *(const short8*)(VT + (((h * 16 + lo) * 128 + ko) ^ ((lo & 7) << 4)));
            short8 bp = *(const short8*)(Ps + ((trow * 128 + ko) ^ tswz));
            ot = __builtin_amdgcn_mfma_f32_16x16x32_bf16(av, bp, ot, 0, 0, 0);
        }
        uint2 ow_;
        ow_.x = pkbf(ot[0], ot[1]); ow_.y = pkbf(ot[2], ot[3]);
        *(uint2*)(Xo + ((trow * 128 + (h * 16 + hi * 4) * 2) ^ tswz)) = ow_;
    }
    __syncthreads();  // barrier 3: Xo complete; Ps region dead again

    // ---- proj ----
    f32x4 cy[4];
#pragma unroll
    for (int mt = 0; mt < 4; ++mt) cy[mt] = (f32x4){0.f, 0.f, 0.f, 0.f};
#pragma unroll
    for (int ks = 0; ks < 2; ++ks) {
        const int koff = hi * 8 + ks * 32;
        short8 bw = *(const short8*)(projwb + (w * 16 + lo) * 64 + koff);
#pragma unroll
        for (int mt = 0; mt < 4; ++mt) {
            short8 ax = *(const short8*)(Xo + (((mt * 16 + lo) * 128 + koff * 2) ^ ((lo & 7) << 4)));
            cy[mt] = __builtin_amdgcn_mfma_f32_16x16x32_bf16(ax, bw, cy[mt], 0, 0, 0);
        }
    }
    const float pb = projb[w * 16 + lo];

    if constexpr (FUSE == 0) {
        // stage Y (bf16, linear [tok][64ch]) in Ps region -> coalesced stores
        unsigned short* Y = (unsigned short*)Ps;
#pragma unroll
        for (int mt = 0; mt < 4; ++mt) {
#pragma unroll
            for (int r = 0; r < 4; ++r) {
                const int tok = mt * 16 + hi * 4 + r;
                Y[tok * 64 + w * 16 + lo] = f2bf(cy[mt][r] + pb);
            }
        }
        __syncthreads();  // barrier 4: Y complete
        {
            const int t = tid >> 2, c0 = (tid & 3) * 16;
            const int pix = pixbase + (t >> 3) * 128 + (t & 7);
            const uint4* yp = (const uint4*)(Y + t * 64 + c0);
            uint4* dp = (uint4*)(dst + (size_t)pix * 64 + c0);
            dp[0] = yp[0];
            dp[1] = yp[1];
        }
    } else {
        // fused 1x1 outconv: out[tok] = sum_ch (Y[tok][ch]) * ow[ch] + ob
        const float owv = outw[w * 16 + lo];
        float* red = (float*)VT;  // [64 tok][4 waves]
#pragma unroll
        for (int mt = 0; mt < 4; ++mt) {
#pragma unroll
            for (int r = 0; r < 4; ++r) {
                float s = (cy[mt][r] + pb) * owv;
                s += __shfl_xor(s, 1);
                s += __shfl_xor(s, 2);
                s += __shfl_xor(s, 4);
                s += __shfl_xor(s, 8);
                if (lo == 0) red[(mt * 16 + hi * 4 + r) * 4 + w] = s;
            }
        }
        __syncthreads();
        if (tid < 64) {
            const int tok = tid;
            float4 rv = *(const float4*)(red + tok * 4);
            const int pix = pixbase + (tok >> 3) * 128 + (tok & 7);
            out[pix] = (rv.x + rv.y) + (rv.z + rv.w) + outb[0];
        }
    }
}

// ---------------------------------------------------------------------------
extern "C" void kernel_launch(void* const* d_in, const int* in_sizes, int n_in,
                              void* d_out, int out_size, void* d_ws, size_t ws_size,
                              hipStream_t stream)
{
    const float* x      = (const float*)d_in[0];
    const float* cw0    = (const float*)d_in[1];
    const float* cb0    = (const float*)d_in[2];
    const float* pxw0   = (const float*)d_in[3];
    const float* pyw0   = (const float*)d_in[4];
    const float* qkvw0  = (const float*)d_in[5];
    const float* projw0 = (const float*)d_in[6];
    const float* projb0 = (const float*)d_in[7];
    const float* cw1    = (const float*)d_in[8];
    const float* cb1    = (const float*)d_in[9];
    const float* pxw1   = (const float*)d_in[10];
    const float* pyw1   = (const float*)d_in[11];
    const float* qkvw1  = (const float*)d_in[12];
    const float* projw1 = (const float*)d_in[13];
    const float* projb1 = (const float*)d_in[14];
    const float* outw   = (const float*)d_in[15];
    const float* outb   = (const float*)d_in[16];

    const size_t BUF = (size_t)16 * 128 * 128 * 64 * sizeof(float);  // 64 MB slots
    char* ws = (char*)d_ws;
    unsigned short* bufA = (unsigned short*)ws;           // h2pre0 / h2pre1
    unsigned short* bufB = (unsigned short*)(ws + BUF);   // h0
    char* wsx = ws + 2 * BUF;
    unsigned short* pwc  = (unsigned short*)(wsx);            // [0,      368640)
    float* pw0           = (float*)(wsx + 369664);            // [369664, 381184)
    unsigned short* qb0  = (unsigned short*)(wsx + 381440);   // [381440, 406016)
    unsigned short* pjb0 = (unsigned short*)(wsx + 406016);   // [406016, 414208)
    unsigned short* qb1  = (unsigned short*)(wsx + 414208);   // [414208, 438784)
    unsigned short* pjb1 = (unsigned short*)(wsx + 438784);   // [438784, 446976)

    repack_kernel<<<860, 256, 0, stream>>>(
        cw0, pxw0, pyw0, cw1, pxw1, pyw1,
        qkvw0, projw0, qkvw1, projw1,
        pwc, pw0, qb0, pjb0, qb1, pjb1);

    gates1_kernel<<<4096, 256, 0, stream>>>(x, pw0, cb0, bufA);
    attn_kernel<0><<<4096, 256, 0, stream>>>(bufA, qb0, pjb0, projb0, bufB,
                                             nullptr, nullptr, nullptr);
    gates64_kernel<<<4096, 256, 0, stream>>>(bufB, pwc, cb1, bufA);
    attn_kernel<1><<<4096, 256, 0, stream>>>(bufA, qb1, pjb1, projb1, nullptr,
                                             outw, outb, (float*)d_out);
}